// Round 10
// baseline (73.986 us; speedup 1.0000x reference)
//
#include <hip/hip_runtime.h>
#include <hip/hip_bf16.h>

#define BB 8
#define NN 2048
#define FF 128

typedef __bf16 bf16x8 __attribute__((ext_vector_type(8)));
typedef float f32x4 __attribute__((ext_vector_type(4)));
typedef float f32x16 __attribute__((ext_vector_type(16)));

__device__ __forceinline__ void gload_lds16(const void* g, void* l) {
    __builtin_amdgcn_global_load_lds(
        (const __attribute__((address_space(1))) unsigned int*)g,
        (__attribute__((address_space(3))) unsigned int*)l, 16, 0, 0);
}

// ---------------------------------------------------------------------------
// Kernel A: Wh = h @ W (bf16 MFMA), src/dst rowvecs, fragB packed in
// 32x32x16 MFMA B-fragment order (unchanged — passed refcheck):
//   fragB[((b*128+jt)*4+ft)*64 + lane][e] =
//     Wh[jt*16 + (lane>>5)*8 + e][ft*32 + (lane&31)]
// ---------------------------------------------------------------------------
__global__ __launch_bounds__(256) void wh_kernel(
    const float* __restrict__ h, const float* __restrict__ W,
    const float* __restrict__ a, __bf16* __restrict__ fragB,
    float* __restrict__ srcg, float* __restrict__ dstg)
{
    __shared__ float  s_h[32][132];
    __shared__ __bf16 s_wh[32][132];
    __shared__ float  s_s[2][32];
    __shared__ float  s_d[2][32];

    const int bid = blockIdx.x;
    const int b   = bid >> 6;
    const int J   = bid & 63;
    const int r0  = J * 32;
    const int t   = threadIdx.x;
    const int w   = t >> 6;
    const int l   = t & 63;
    const int itile = w & 1;
    const int fh    = w >> 1;
    const int g     = l >> 4;
    const int c16   = l & 15;

#pragma unroll
    for (int i = 0; i < 4; ++i) {
        const int idx = t + i * 256;
        const int r   = idx >> 5;
        const int c4  = idx & 31;
        *(f32x4*)&s_h[r][c4 * 4] =
            *(const f32x4*)(h + (size_t)(b * NN + r0 + r) * FF + c4 * 4);
    }
    __syncthreads();

    const float* hrow = &s_h[itile * 16 + c16][0];
    f32x4 acc[4] = {};

#pragma unroll
    for (int kt = 0; kt < 4; ++kt) {
        const int k0 = kt * 32 + g * 8;
        f32x4 h0 = *(const f32x4*)(hrow + k0);
        f32x4 h1 = *(const f32x4*)(hrow + k0 + 4);
        bf16x8 af;
        af[0]=(__bf16)h0[0]; af[1]=(__bf16)h0[1]; af[2]=(__bf16)h0[2]; af[3]=(__bf16)h0[3];
        af[4]=(__bf16)h1[0]; af[5]=(__bf16)h1[1]; af[6]=(__bf16)h1[2]; af[7]=(__bf16)h1[3];
#pragma unroll
        for (int ft = 0; ft < 4; ++ft) {
            const int c = (fh * 4 + ft) * 16 + c16;
            bf16x8 bf;
#pragma unroll
            for (int e = 0; e < 8; ++e) bf[e] = (__bf16)W[(k0 + e) * FF + c];
            acc[ft] = __builtin_amdgcn_mfma_f32_16x16x32_bf16(af, bf, acc[ft], 0, 0, 0);
        }
    }

    float a1v[4], a2v[4];
#pragma unroll
    for (int ft = 0; ft < 4; ++ft) {
        const int c = (fh * 4 + ft) * 16 + c16;
        a1v[ft] = a[c];
        a2v[ft] = a[FF + c];
    }
#pragma unroll
    for (int r = 0; r < 4; ++r) {
        float s = 0.f, d2 = 0.f;
#pragma unroll
        for (int ft = 0; ft < 4; ++ft) {
            s  += acc[ft][r] * a1v[ft];
            d2 += acc[ft][r] * a2v[ft];
        }
#pragma unroll
        for (int m = 1; m <= 8; m <<= 1) {
            s  += __shfl_xor(s,  m);
            d2 += __shfl_xor(d2, m);
        }
        if (c16 == 0) {
            s_s[fh][itile * 16 + g * 4 + r] = s;
            s_d[fh][itile * 16 + g * 4 + r] = d2;
        }
    }

#pragma unroll
    for (int ft = 0; ft < 4; ++ft)
#pragma unroll
        for (int r = 0; r < 4; ++r)
            s_wh[itile * 16 + g * 4 + r][(fh * 4 + ft) * 16 + c16] = (__bf16)acc[ft][r];

    __syncthreads();

#pragma unroll
    for (int e2 = 0; e2 < 2; ++e2) {
        const int ent  = t + e2 * 256;
        const int tile = ent >> 6;
        const int jl   = tile >> 2;
        const int ft   = tile & 3;
        const int lE   = ent & 63;
        const int rowE = jl * 16 + (lE >> 5) * 8;
        const int colE = ft * 32 + (lE & 31);
        bf16x8 v;
#pragma unroll
        for (int ee = 0; ee < 8; ++ee) v[ee] = s_wh[rowE + ee][colE];
        *(bf16x8*)(fragB + (((size_t)(b * 128 + J * 2 + jl) * 4 + ft) * 64 + lE) * 8) = v;
    }

    if (t < 32) {
        srcg[b * NN + r0 + t] = s_s[0][t] + s_s[1][t];
        dstg[b * NN + r0 + t] = s_d[0][t] + s_d[1][t];
    }
}

// ---------------------------------------------------------------------------
// Kernel B v10: v8 with the per-step sched_barrier(0) REMOVED.
// Memory ops (gload_lds DMA, ds_read) remain ordered by the asm "memory"
// clobbers (ledger + LDS slot WAR safety intact); register-only work (exp
// chain, bf16 pack, MFMA) may now float across step boundaries so the
// compiler can software-pipeline consecutive steps.
// 4 waves = 4 j-quarters, 32 steps x 16 j, M=32 mfma_f32_32x32x16_bf16.
// Per step: issue F(kt+1)[4 DMA], A(kt+2)[2 DMA]; s_waitcnt vmcnt(8)
// retires exactly {A(kt) age-2, F(kt) age-1}. Zero inner barriers.
// ---------------------------------------------------------------------------
__global__ __launch_bounds__(256, 2) void attn_kernel(
    const int* __restrict__ adj, const __bf16* __restrict__ fragB,
    const float* __restrict__ srcg, const float* __restrict__ dstg,
    float* __restrict__ out)
{
    __shared__ char s_all[74240];
    // [0,32768):      adj  4 slots x 2048 per wave (q*8192)
    // [32768,65536):  frag 2 slots x 4096 per wave (q*8192)
    // [65536,73728):  dst  2048 per wave
    // [73728,74240):  s_ps (tail)

    const int bid0 = blockIdx.x;
    const int bid  = (bid0 & 7) * 64 + (bid0 >> 3);   // bijective XCD swizzle
    const int b    = bid >> 6;
    const int I0   = (bid & 63) * 32;
    const int t    = threadIdx.x;
    const int q    = t >> 6;                  // wave = j-quarter
    const int l    = t & 63;
    const int r31  = l & 31;
    const int hi   = l >> 5;

    char* awave = s_all + q * 8192;
    char* fwave = s_all + 32768 + q * 8192;
    char* dstw  = s_all + 65536 + q * 2048;
    float* s_ps = (float*)(s_all + 73728);

    // ---- plain src load, fully drained BEFORE the DMA ledger starts ----
    const float sv = srcg[b * NN + I0 + r31];
    asm volatile("s_waitcnt vmcnt(0) lgkmcnt(0)" ::: "memory");

    const char* aSrc = (const char*)adj
        + ((size_t)(b * NN + I0 + r31) * NN + q * 512) * 4 + hi * 32;
    const char* fBase = (const char*)fragB
        + (size_t)(b * 128 + q * 32) * 4096 + (size_t)l * 16;
    const char* dSrc = (const char*)(dstg + (size_t)b * NN + q * 512) + l * 16;

#define ISSUE_A(ki_, sl_) {                                                   \
        const char* pa_ = aSrc + (size_t)(ki_) * 64;                          \
        gload_lds16(pa_,      awave + (sl_) * 2048 + l * 16);                 \
        gload_lds16(pa_ + 16, awave + (sl_) * 2048 + 1024 + l * 16); }
#define ISSUE_F(ki_, sl_) {                                                   \
        const char* pf_ = fBase + (size_t)(ki_) * 4096;                       \
        char* fd_ = fwave + (sl_) * 4096 + l * 16;                            \
        gload_lds16(pf_,        fd_);                                         \
        gload_lds16(pf_ + 1024, fd_ + 1024);                                  \
        gload_lds16(pf_ + 2048, fd_ + 2048);                                  \
        gload_lds16(pf_ + 3072, fd_ + 3072); }

    // prologue ledger (issue order matters): dst(2), A0(2), F0(4), A1(2)
    gload_lds16(dSrc,        dstw + l * 16);
    gload_lds16(dSrc + 1024, dstw + 1024 + l * 16);
    ISSUE_A(0, 0);
    ISSUE_F(0, 0);
    ISSUE_A(1, 1);

    f32x16 acc0 = {}, acc1 = {}, acc2 = {}, acc3 = {};
    float psum = 0.f;

#pragma unroll 4
    for (int kt = 0; kt < 32; ++kt) {
        const int kF = (kt + 1 < 32) ? kt + 1 : 31;   // clamped dummies keep
        const int kA = (kt + 2 < 32) ? kt + 2 : 31;   // the ledger uniform
        ISSUE_F(kF, (kt + 1) & 1);
        ISSUE_A(kA, (kt + 2) & 3);
        // retires exactly A(kt) [age 2 steps] + F(kt) [age 1 step]
        asm volatile("s_waitcnt vmcnt(8)" ::: "memory");
        // NOTE: no sched_barrier(0) here — register-only ops may pipeline
        // across steps; memory ops stay ordered by the asm memory clobber.

        const char* asl = awave + (kt & 3) * 2048 + l * 16;
        const int4 A0 = *(const int4*)(asl);
        const int4 A1 = *(const int4*)(asl + 1024);
        const f32x4 d0 = *(const f32x4*)(dstw + kt * 64 + hi * 32);
        const f32x4 d1 = *(const f32x4*)(dstw + kt * 64 + hi * 32 + 16);
        const int   am[8] = {A0.x, A0.y, A0.z, A0.w, A1.x, A1.y, A1.z, A1.w};
        const float dv[8] = {d0[0], d0[1], d0[2], d0[3], d1[0], d1[1], d1[2], d1[3]};

        bf16x8 af;
#pragma unroll
        for (int e = 0; e < 8; ++e) {
            float x = sv + dv[e];
            x = fmaxf(x, 0.2f * x);          // leaky_relu 0.2
            float p = __expf(x);             // bounded, no max-sub needed
            p = (am[e] > 0) ? p : 0.f;
            psum += p;
            af[e] = (__bf16)p;
        }

        const char* fsl = fwave + (kt & 1) * 4096 + l * 16;
        const bf16x8 b0 = *(const bf16x8*)(fsl);
        const bf16x8 b1 = *(const bf16x8*)(fsl + 1024);
        const bf16x8 b2 = *(const bf16x8*)(fsl + 2048);
        const bf16x8 b3 = *(const bf16x8*)(fsl + 3072);
        acc0 = __builtin_amdgcn_mfma_f32_32x32x16_bf16(af, b0, acc0, 0, 0, 0);
        acc1 = __builtin_amdgcn_mfma_f32_32x32x16_bf16(af, b1, acc1, 0, 0, 0);
        acc2 = __builtin_amdgcn_mfma_f32_32x32x16_bf16(af, b2, acc2, 0, 0, 0);
        acc3 = __builtin_amdgcn_mfma_f32_32x32x16_bf16(af, b3, acc3, 0, 0, 0);
    }
#undef ISSUE_A
#undef ISSUE_F

    asm volatile("s_waitcnt vmcnt(0)" ::: "memory");  // drain dummies before LDS reuse

    // denom partial: lanes l and l^32 cover the same row, disjoint j
    psum += __shfl_xor(psum, 32);
    if (l < 32) s_ps[q * 32 + l] = psum;

    // ---- 4-way j-partial combine (reuse pipe LDS: [4 q][4 ft][64][17]) ----
    __syncthreads();
    float* comb = (float*)s_all;
    {
        float* cb = comb + ((q * 4 + 0) * 64 + l) * 17;
#pragma unroll
        for (int r = 0; r < 16; ++r) cb[r] = acc0[r];
        cb = comb + ((q * 4 + 1) * 64 + l) * 17;
#pragma unroll
        for (int r = 0; r < 16; ++r) cb[r] = acc1[r];
        cb = comb + ((q * 4 + 2) * 64 + l) * 17;
#pragma unroll
        for (int r = 0; r < 16; ++r) cb[r] = acc2[r];
        cb = comb + ((q * 4 + 3) * 64 + l) * 17;
#pragma unroll
        for (int r = 0; r < 16; ++r) cb[r] = acc3[r];
    }
    __syncthreads();

    // wave q owns output ft-tile q
    f32x16 tot;
#pragma unroll
    for (int r = 0; r < 16; ++r)
        tot[r] = comb[((0 * 4 + q) * 64 + l) * 17 + r]
               + comb[((1 * 4 + q) * 64 + l) * 17 + r]
               + comb[((2 * 4 + q) * 64 + l) * 17 + r]
               + comb[((3 * 4 + q) * 64 + l) * 17 + r];

    const float dtot = s_ps[0 * 32 + r31] + s_ps[1 * 32 + r31]
                     + s_ps[2 * 32 + r31] + s_ps[3 * 32 + r31];
    const float rin  = 1.f / dtot;

    // C layout (32x32): col = l&31, row = (r&3) + 8*(r>>2) + 4*hi
#pragma unroll
    for (int r = 0; r < 16; ++r) {
        const int row  = (r & 3) + 8 * (r >> 2) + 4 * hi;
        const float dv2 = __shfl(rin, row);
        out[(size_t)(b * NN + I0 + row) * FF + q * 32 + r31] = tot[r] * dv2;
    }
}

// ---------------------------------------------------------------------------
// DIAGNOSTIC this round: attn launched TWICE (dummy then real, identical
// args/output -> deterministic). dur_us = wh + 2*attn. Combined with round
// 8's (wh + attn_v8 = 42.3 us) this splits wh vs attn across rounds.
// ---------------------------------------------------------------------------
extern "C" void kernel_launch(void* const* d_in, const int* in_sizes, int n_in,
                              void* d_out, int out_size, void* d_ws, size_t ws_size,
                              hipStream_t stream)
{
    const float* h   = (const float*)d_in[0];
    const int*   adj = (const int*)d_in[1];
    const float* W   = (const float*)d_in[2];
    const float* a   = (const float*)d_in[3];
    float* out = (float*)d_out;

    char* ws = (char*)d_ws;
    __bf16* fragB = (__bf16*)ws;                              // 4 MiB
    float*  srcg  = (float*)(ws + (4 << 20));                 // 64 KiB
    float*  dstg  = (float*)(ws + (4 << 20) + (64 << 10));    // 64 KiB

    wh_kernel<<<512, 256, 0, stream>>>(h, W, a, fragB, srcg, dstg);
    attn_kernel<<<512, 256, 0, stream>>>(adj, fragB, srcg, dstg, out);  // timing dummy
    attn_kernel<<<512, 256, 0, stream>>>(adj, fragB, srcg, dstg, out);  // real
}

// Round 11
// 43.840 us; speedup vs baseline: 1.6876x; 1.6876x over previous
//
#include <hip/hip_runtime.h>
#include <hip/hip_bf16.h>

#define BB 8
#define NN 2048
#define FF 128

typedef __bf16 bf16x8 __attribute__((ext_vector_type(8)));
typedef float f32x4 __attribute__((ext_vector_type(4)));
typedef float f32x16 __attribute__((ext_vector_type(16)));

__device__ __forceinline__ void gload_lds16(const void* g, void* l) {
    __builtin_amdgcn_global_load_lds(
        (const __attribute__((address_space(1))) unsigned int*)g,
        (__attribute__((address_space(3))) unsigned int*)l, 16, 0, 0);
}

// ---------------------------------------------------------------------------
// Kernel A: Wh = h @ W (bf16 MFMA), src/dst rowvecs, fragB packed in
// 32x32x16 MFMA B-fragment order (unchanged — passed refcheck):
//   fragB[((b*128+jt)*4+ft)*64 + lane][e] =
//     Wh[jt*16 + (lane>>5)*8 + e][ft*32 + (lane&31)]
// ---------------------------------------------------------------------------
__global__ __launch_bounds__(256) void wh_kernel(
    const float* __restrict__ h, const float* __restrict__ W,
    const float* __restrict__ a, __bf16* __restrict__ fragB,
    float* __restrict__ srcg, float* __restrict__ dstg)
{
    __shared__ float  s_h[32][132];
    __shared__ __bf16 s_wh[32][132];
    __shared__ float  s_s[2][32];
    __shared__ float  s_d[2][32];

    const int bid = blockIdx.x;
    const int b   = bid >> 6;
    const int J   = bid & 63;
    const int r0  = J * 32;
    const int t   = threadIdx.x;
    const int w   = t >> 6;
    const int l   = t & 63;
    const int itile = w & 1;
    const int fh    = w >> 1;
    const int g     = l >> 4;
    const int c16   = l & 15;

#pragma unroll
    for (int i = 0; i < 4; ++i) {
        const int idx = t + i * 256;
        const int r   = idx >> 5;
        const int c4  = idx & 31;
        *(f32x4*)&s_h[r][c4 * 4] =
            *(const f32x4*)(h + (size_t)(b * NN + r0 + r) * FF + c4 * 4);
    }
    __syncthreads();

    const float* hrow = &s_h[itile * 16 + c16][0];
    f32x4 acc[4] = {};

#pragma unroll
    for (int kt = 0; kt < 4; ++kt) {
        const int k0 = kt * 32 + g * 8;
        f32x4 h0 = *(const f32x4*)(hrow + k0);
        f32x4 h1 = *(const f32x4*)(hrow + k0 + 4);
        bf16x8 af;
        af[0]=(__bf16)h0[0]; af[1]=(__bf16)h0[1]; af[2]=(__bf16)h0[2]; af[3]=(__bf16)h0[3];
        af[4]=(__bf16)h1[0]; af[5]=(__bf16)h1[1]; af[6]=(__bf16)h1[2]; af[7]=(__bf16)h1[3];
#pragma unroll
        for (int ft = 0; ft < 4; ++ft) {
            const int c = (fh * 4 + ft) * 16 + c16;
            bf16x8 bf;
#pragma unroll
            for (int e = 0; e < 8; ++e) bf[e] = (__bf16)W[(k0 + e) * FF + c];
            acc[ft] = __builtin_amdgcn_mfma_f32_16x16x32_bf16(af, bf, acc[ft], 0, 0, 0);
        }
    }

    float a1v[4], a2v[4];
#pragma unroll
    for (int ft = 0; ft < 4; ++ft) {
        const int c = (fh * 4 + ft) * 16 + c16;
        a1v[ft] = a[c];
        a2v[ft] = a[FF + c];
    }
#pragma unroll
    for (int r = 0; r < 4; ++r) {
        float s = 0.f, d2 = 0.f;
#pragma unroll
        for (int ft = 0; ft < 4; ++ft) {
            s  += acc[ft][r] * a1v[ft];
            d2 += acc[ft][r] * a2v[ft];
        }
#pragma unroll
        for (int m = 1; m <= 8; m <<= 1) {
            s  += __shfl_xor(s,  m);
            d2 += __shfl_xor(d2, m);
        }
        if (c16 == 0) {
            s_s[fh][itile * 16 + g * 4 + r] = s;
            s_d[fh][itile * 16 + g * 4 + r] = d2;
        }
    }

#pragma unroll
    for (int ft = 0; ft < 4; ++ft)
#pragma unroll
        for (int r = 0; r < 4; ++r)
            s_wh[itile * 16 + g * 4 + r][(fh * 4 + ft) * 16 + c16] = (__bf16)acc[ft][r];

    __syncthreads();

#pragma unroll
    for (int e2 = 0; e2 < 2; ++e2) {
        const int ent  = t + e2 * 256;
        const int tile = ent >> 6;
        const int jl   = tile >> 2;
        const int ft   = tile & 3;
        const int lE   = ent & 63;
        const int rowE = jl * 16 + (lE >> 5) * 8;
        const int colE = ft * 32 + (lE & 31);
        bf16x8 v;
#pragma unroll
        for (int ee = 0; ee < 8; ++ee) v[ee] = s_wh[rowE + ee][colE];
        *(bf16x8*)(fragB + (((size_t)(b * 128 + J * 2 + jl) * 4 + ft) * 64 + lE) * 8) = v;
    }

    if (t < 32) {
        srcg[b * NN + r0 + t] = s_s[0][t] + s_s[1][t];
        dstg[b * NN + r0 + t] = s_d[0][t] + s_d[1][t];
    }
}

// ---------------------------------------------------------------------------
// Kernel B v11: FAT STEPS — 16 steps x 32 j/wave (K=32 per step, two K=16
// MFMA slices). Per-step fixed cost (measured ~2400-2700 cy invariant across
// v2..v10) is amortized over 2x volume; v2->v4 showed exactly this scaling.
// 4 waves = 4 j-quarters. adj: 4-slot LDS DMA pipe (4 KB/step, distance 2).
// frag: asm register loads (8 x dwordx4/step, distance 1, v9-proven).
// Ledger: prologue {dst2, A0(4), F0(8), A1(4)}; per step issue F(kt+1)[8],
// A(kt+2)[4], wait vmcnt(16) -> retires exactly {A(kt), F(kt)}.
// Zero inner barriers; combine tail v8-verbatim.
// ---------------------------------------------------------------------------
__global__ __launch_bounds__(256, 2) void attn_kernel(
    const int* __restrict__ adj, const __bf16* __restrict__ fragB,
    const float* __restrict__ srcg, const float* __restrict__ dstg,
    float* __restrict__ out)
{
    __shared__ char s_all[74240];
    // [0,65536):      adj 4 slots x 4096 per wave (q*16384)
    // [65536,73728):  dst 2048 per wave
    // [73728,74240):  s_ps
    // tail combine reuses [0,69632)

    const int bid0 = blockIdx.x;
    const int bid  = (bid0 & 7) * 64 + (bid0 >> 3);   // bijective XCD swizzle
    const int b    = bid >> 6;
    const int I0   = (bid & 63) * 32;
    const int t    = threadIdx.x;
    const int q    = t >> 6;                  // wave = j-quarter
    const int l    = t & 63;
    const int r31  = l & 31;
    const int hi   = l >> 5;

    char* awave = s_all + q * 16384;
    char* dstw  = s_all + 65536 + q * 2048;
    float* s_ps = (float*)(s_all + 73728);

    // ---- plain src load, fully drained BEFORE the DMA ledger starts ----
    const float sv = srcg[b * NN + I0 + r31];
    asm volatile("s_waitcnt vmcnt(0) lgkmcnt(0)" ::: "memory");

    // adj source: lane covers (row = I0 + (l&31), 16B-unit m*2 + hi of the
    // 128-B step window). aSrc includes row*stride + q-slice + hi*16.
    const char* aSrc = (const char*)adj
        + ((size_t)(b * NN + I0 + r31) * NN + q * 512) * 4 + hi * 16;
    const char* fBase = (const char*)fragB
        + (size_t)(b * 128 + q * 32) * 4096 + (size_t)l * 16;
    const char* dSrc = (const char*)(dstg + (size_t)b * NN + q * 512) + l * 16;

#define ISSUE_A(ki_) {                                                        \
        const char* pa_ = aSrc + (size_t)(ki_) * 128;                         \
        char* ad_ = awave + ((ki_) & 3) * 4096 + l * 16;                      \
        gload_lds16(pa_,      ad_);                                           \
        gload_lds16(pa_ + 32, ad_ + 1024);                                    \
        gload_lds16(pa_ + 64, ad_ + 2048);                                    \
        gload_lds16(pa_ + 96, ad_ + 3072); }

#define ISSUE_F(ki_, B0_, B1_, B2_, B3_, B4_, B5_, B6_, B7_) {                \
        const char* p0_ = fBase + (size_t)(ki_) * 8192;                       \
        const char* p1_ = p0_ + 4096;                                         \
        asm volatile("global_load_dwordx4 %0, %1, off"                        \
                     : "=&v"(B0_) : "v"(p0_));                                \
        asm volatile("global_load_dwordx4 %0, %1, off offset:1024"            \
                     : "=&v"(B1_) : "v"(p0_));                                \
        asm volatile("global_load_dwordx4 %0, %1, off offset:2048"            \
                     : "=&v"(B2_) : "v"(p0_));                                \
        asm volatile("global_load_dwordx4 %0, %1, off offset:3072"            \
                     : "=&v"(B3_) : "v"(p0_));                                \
        asm volatile("global_load_dwordx4 %0, %1, off"                        \
                     : "=&v"(B4_) : "v"(p1_));                                \
        asm volatile("global_load_dwordx4 %0, %1, off offset:1024"            \
                     : "=&v"(B5_) : "v"(p1_));                                \
        asm volatile("global_load_dwordx4 %0, %1, off offset:2048"            \
                     : "=&v"(B6_) : "v"(p1_));                                \
        asm volatile("global_load_dwordx4 %0, %1, off offset:3072"            \
                     : "=&v"(B7_) : "v"(p1_)); }

    bf16x8 Fa0, Fa1, Fa2, Fa3, Fa4, Fa5, Fa6, Fa7;
    bf16x8 Fb0, Fb1, Fb2, Fb3, Fb4, Fb5, Fb6, Fb7;
    f32x16 acc0 = {}, acc1 = {}, acc2 = {}, acc3 = {};
    float psum = 0.f;

    // prologue ledger: dst(2), A(0)[4], F(0)[8], A(1)[4] = 18 outstanding
    gload_lds16(dSrc,        dstw + l * 16);
    gload_lds16(dSrc + 1024, dstw + 1024 + l * 16);
    ISSUE_A(0);
    ISSUE_F(0, Fa0, Fa1, Fa2, Fa3, Fa4, Fa5, Fa6, Fa7);
    ISSUE_A(1);

#define STEP(kt_, C0_,C1_,C2_,C3_,C4_,C5_,C6_,C7_, N0_,N1_,N2_,N3_,N4_,N5_,N6_,N7_) { \
        const int kF_ = ((kt_) + 1 < 16) ? (kt_) + 1 : 15;                    \
        const int kA_ = ((kt_) + 2 < 16) ? (kt_) + 2 : 15;                    \
        ISSUE_F(kF_, N0_, N1_, N2_, N3_, N4_, N5_, N6_, N7_);                 \
        ISSUE_A(kA_);                                                         \
        asm volatile("s_waitcnt vmcnt(16)" ::: "memory");                     \
        /* adj: 4 int4 reads for units {hi*2, hi*2+1, 4+hi*2, 5+hi*2} */      \
        const char* ab_ = awave + ((kt_) & 3) * 4096 + hi * 1024 + r31 * 16;  \
        const int4 A00_ = *(const int4*)(ab_);                                \
        const int4 A01_ = *(const int4*)(ab_ + 512);                          \
        const int4 A10_ = *(const int4*)(ab_ + 2048);                         \
        const int4 A11_ = *(const int4*)(ab_ + 2048 + 512);                   \
        const f32x4 d00_ = *(const f32x4*)(dstw + (kt_) * 128 + hi * 32);     \
        const f32x4 d01_ = *(const f32x4*)(dstw + (kt_) * 128 + hi * 32 + 16);\
        const f32x4 d10_ = *(const f32x4*)(dstw + (kt_) * 128 + 64 + hi * 32);\
        const f32x4 d11_ = *(const f32x4*)(dstw + (kt_) * 128 + 64 + hi * 32 + 16);\
        const int   am0_[8] = {A00_.x, A00_.y, A00_.z, A00_.w,                \
                               A01_.x, A01_.y, A01_.z, A01_.w};               \
        const int   am1_[8] = {A10_.x, A10_.y, A10_.z, A10_.w,                \
                               A11_.x, A11_.y, A11_.z, A11_.w};               \
        const float dv0_[8] = {d00_[0], d00_[1], d00_[2], d00_[3],            \
                               d01_[0], d01_[1], d01_[2], d01_[3]};           \
        const float dv1_[8] = {d10_[0], d10_[1], d10_[2], d10_[3],            \
                               d11_[0], d11_[1], d11_[2], d11_[3]};           \
        bf16x8 af0_, af1_;                                                    \
        _Pragma("unroll")                                                     \
        for (int e = 0; e < 8; ++e) {                                         \
            float x0 = sv + dv0_[e];                                          \
            x0 = fmaxf(x0, 0.2f * x0);                                        \
            float p0 = __expf(x0);                                            \
            p0 = (am0_[e] > 0) ? p0 : 0.f;                                    \
            psum += p0;                                                       \
            af0_[e] = (__bf16)p0;                                             \
            float x1 = sv + dv1_[e];                                          \
            x1 = fmaxf(x1, 0.2f * x1);                                        \
            float p1 = __expf(x1);                                            \
            p1 = (am1_[e] > 0) ? p1 : 0.f;                                    \
            psum += p1;                                                       \
            af1_[e] = (__bf16)p1;                                             \
        }                                                                     \
        acc0 = __builtin_amdgcn_mfma_f32_32x32x16_bf16(af0_, C0_, acc0, 0, 0, 0); \
        acc1 = __builtin_amdgcn_mfma_f32_32x32x16_bf16(af0_, C1_, acc1, 0, 0, 0); \
        acc2 = __builtin_amdgcn_mfma_f32_32x32x16_bf16(af0_, C2_, acc2, 0, 0, 0); \
        acc3 = __builtin_amdgcn_mfma_f32_32x32x16_bf16(af0_, C3_, acc3, 0, 0, 0); \
        acc0 = __builtin_amdgcn_mfma_f32_32x32x16_bf16(af1_, C4_, acc0, 0, 0, 0); \
        acc1 = __builtin_amdgcn_mfma_f32_32x32x16_bf16(af1_, C5_, acc1, 0, 0, 0); \
        acc2 = __builtin_amdgcn_mfma_f32_32x32x16_bf16(af1_, C6_, acc2, 0, 0, 0); \
        acc3 = __builtin_amdgcn_mfma_f32_32x32x16_bf16(af1_, C7_, acc3, 0, 0, 0); }

    for (int kt2 = 0; kt2 < 16; kt2 += 2) {
        STEP(kt2 + 0, Fa0,Fa1,Fa2,Fa3,Fa4,Fa5,Fa6,Fa7, Fb0,Fb1,Fb2,Fb3,Fb4,Fb5,Fb6,Fb7);
        STEP(kt2 + 1, Fb0,Fb1,Fb2,Fb3,Fb4,Fb5,Fb6,Fb7, Fa0,Fa1,Fa2,Fa3,Fa4,Fa5,Fa6,Fa7);
    }
#undef STEP
#undef ISSUE_A
#undef ISSUE_F

    asm volatile("s_waitcnt vmcnt(0) lgkmcnt(0)" ::: "memory");  // drain dummies

    // denom partial: lanes l and l^32 cover the same row, disjoint j
    psum += __shfl_xor(psum, 32);
    if (l < 32) s_ps[q * 32 + l] = psum;

    // ---- 4-way j-partial combine (reuse pipe LDS: [4 q][4 ft][64][17]) ----
    __syncthreads();
    float* comb = (float*)s_all;
    {
        float* cb = comb + ((q * 4 + 0) * 64 + l) * 17;
#pragma unroll
        for (int r = 0; r < 16; ++r) cb[r] = acc0[r];
        cb = comb + ((q * 4 + 1) * 64 + l) * 17;
#pragma unroll
        for (int r = 0; r < 16; ++r) cb[r] = acc1[r];
        cb = comb + ((q * 4 + 2) * 64 + l) * 17;
#pragma unroll
        for (int r = 0; r < 16; ++r) cb[r] = acc2[r];
        cb = comb + ((q * 4 + 3) * 64 + l) * 17;
#pragma unroll
        for (int r = 0; r < 16; ++r) cb[r] = acc3[r];
    }
    __syncthreads();

    // wave q owns output ft-tile q
    f32x16 tot;
#pragma unroll
    for (int r = 0; r < 16; ++r)
        tot[r] = comb[((0 * 4 + q) * 64 + l) * 17 + r]
               + comb[((1 * 4 + q) * 64 + l) * 17 + r]
               + comb[((2 * 4 + q) * 64 + l) * 17 + r]
               + comb[((3 * 4 + q) * 64 + l) * 17 + r];

    const float dtot = s_ps[0 * 32 + r31] + s_ps[1 * 32 + r31]
                     + s_ps[2 * 32 + r31] + s_ps[3 * 32 + r31];
    const float rin  = 1.f / dtot;

    // C layout (32x32): col = l&31, row = (r&3) + 8*(r>>2) + 4*hi
#pragma unroll
    for (int r = 0; r < 16; ++r) {
        const int row  = (r & 3) + 8 * (r >> 2) + 4 * hi;
        const float dv2 = __shfl(rin, row);
        out[(size_t)(b * NN + I0 + row) * FF + q * 32 + r31] = tot[r] * dv2;
    }
}

// ---------------------------------------------------------------------------
extern "C" void kernel_launch(void* const* d_in, const int* in_sizes, int n_in,
                              void* d_out, int out_size, void* d_ws, size_t ws_size,
                              hipStream_t stream)
{
    const float* h   = (const float*)d_in[0];
    const int*   adj = (const int*)d_in[1];
    const float* W   = (const float*)d_in[2];
    const float* a   = (const float*)d_in[3];
    float* out = (float*)d_out;

    char* ws = (char*)d_ws;
    __bf16* fragB = (__bf16*)ws;                              // 4 MiB
    float*  srcg  = (float*)(ws + (4 << 20));                 // 64 KiB
    float*  dstg  = (float*)(ws + (4 << 20) + (64 << 10));    // 64 KiB

    wh_kernel<<<512, 256, 0, stream>>>(h, W, a, fragB, srcg, dstg);
    attn_kernel<<<512, 256, 0, stream>>>(adj, fragB, srcg, dstg, out);
}